// Round 4
// baseline (212.309 us; speedup 1.0000x reference)
//
#include <hip/hip_runtime.h>

// Problem: S=8192, K=1024, O=4096
// out_q[s,o] = clip(round(int8dot(x[s,:], w[o,:]) * sx*sw/sy[s]), -128, 127)
// d_out = [ out_q as float (S*O) | scale_y (S) ]
//
// R9: 8-phase-template port (m201 structure) for i8.
// BM=BN=256, 512 threads = 8 waves (2Mx4N), wave tile 128x64.
// Ring-3 LDS (3 x (16KB A + 16KB B) = 96 KB, 1 block/CU), 2-deep prefetch,
// counted vmcnt(4) once per K-tile, 4 phases/K-tile:
//   {ds_read subtile | stage 1 load of tile t+2 | BAR | setprio(1) 8xMFMA
//    setprio(0) | BAR}
// B-frags register-resident across the tile's 4 phases. Pack layout identical
// to the verified R5/R8 image (bank-swizzle baked in).

#define S_DIM 8192
#define K_DIM 1024
#define O_DIM 4096
#define BM 256
#define BN 256
#define BK 64
#define NITER (K_DIM / BK)
#define TILE_BYTES (128 * BK)        // 8 KB band-ktile (pack layout unit)
#define BAND_BYTES (NITER * TILE_BYTES)  // 128 KB per 128-row band
#define A_SLOT (2 * TILE_BYTES)      // 16 KB: rows 0-127, 128-255
#define B_SLOT (2 * TILE_BYTES)      // 16 KB: cols 0-127, 128-255

using i32x4 = __attribute__((ext_vector_type(4))) int;

__device__ __forceinline__ void load_lds16(const void* g, void* l) {
  __builtin_amdgcn_global_load_lds(
      (const __attribute__((address_space(1))) void*)g,
      (__attribute__((address_space(3))) void*)l, 16, 0, 0);
}

#define FENCE() asm volatile("" ::: "memory")
#define BARRIER() asm volatile("s_barrier" ::: "memory")

// ---------------- pack: int32 -> int8 into STAGING-TILE layout ----------------
// (byte-identical to the verified R5 pack)
// Layout: tile t = band*16 + ktile (band = row/128, ktile = k/64), 8 KB each.
// Within tile: byte r*64 + cs*16 holds chunk (cs ^ (r&3)) of row band*128+r.
__global__ void pack_kernel(const int* __restrict__ xi, const int* __restrict__ wi,
                            const float* __restrict__ sy,
                            uint4* __restrict__ ap, uint4* __restrict__ bp,
                            float* __restrict__ out_sy) {
  const int tid = blockIdx.x * blockDim.x + threadIdx.x;
  const int nA = S_DIM * K_DIM / 16;  // 512K chunks
  const int nB = O_DIM * K_DIM / 16;  // 256K chunks

  const int* src;
  uint4* dst;
  int j;
  if (tid < nA) {
    src = xi; dst = ap; j = tid;
  } else if (tid < nA + nB) {
    src = wi; dst = bp; j = tid - nA;
  } else {
    return;
  }
  const int t = j >> 9;          // tile index (512 chunks/tile)
  const int idx = j & 511;
  const int r = idx >> 2;        // row within tile 0..127
  const int cs = idx & 3;        // chunk slot
  const int c = cs ^ (r & 3);    // global chunk (swizzle)
  const int band = t >> 4;       // 16 ktiles per band
  const int kt = t & 15;
  const int row = band * 128 + r;
  const int4* s4 = (const int4*)src + row * 256 + kt * 16 + c * 4;
  int4 v0 = s4[0], v1 = s4[1], v2 = s4[2], v3 = s4[3];
  uint4 o;
  o.x = (v0.x & 0xff) | ((v0.y & 0xff) << 8) | ((v0.z & 0xff) << 16) | (((unsigned)v0.w & 0xff) << 24);
  o.y = (v1.x & 0xff) | ((v1.y & 0xff) << 8) | ((v1.z & 0xff) << 16) | (((unsigned)v1.w & 0xff) << 24);
  o.z = (v2.x & 0xff) | ((v2.y & 0xff) << 8) | ((v2.z & 0xff) << 16) | (((unsigned)v2.w & 0xff) << 24);
  o.w = (v3.x & 0xff) | ((v3.y & 0xff) << 8) | ((v3.z & 0xff) << 16) | (((unsigned)v3.w & 0xff) << 24);
  dst[j] = o;
  if (tid < S_DIM) out_sy[tid] = sy[tid];
}

// ---------------- int8 MFMA GEMM, 256x256 tile, 4-phase schedule -------------
// Wave (wm 0..1, wn 0..3) owns rows wm*128..+127, cols wn*64..+63:
// 8 M-frags x 4 N-frags of 16x16x64 = 32 MFMA per K-tile, 4 phases x 8 MFMA.
// Waits: at tile t start, per-wave outstanding = {t:4 oldest, t+1:4 newest};
// vmcnt(4) drains own stage(t); the following BARRIER makes all waves'
// portions visible (each 8KB stage call is written collectively).
// Slot lifetime: stage(t+2) overwrites slot (t+2)%3 == slot(t-1); issued
// only after tile-t's readiness barrier, by which every wave has consumed
// (lgkm-drained, compiler dep-waits + tile-start lgkmcnt(0)) slot t-1.
__global__ __launch_bounds__(512, 2) void gemm_i8_kernel(
    const signed char* __restrict__ Ap,  // tiled-packed x
    const signed char* __restrict__ Bp,  // tiled-packed w
    const float* __restrict__ sx, const float* __restrict__ sw,
    const float* __restrict__ sy, float* __restrict__ out) {
  __shared__ __align__(16) signed char As[3][A_SLOT];  // 48 KB
  __shared__ __align__(16) signed char Bs[3][B_SLOT];  // 48 KB

  const int tid = threadIdx.x;
  const int wave = tid >> 6;
  const int lane = tid & 63;
  const int wm = wave >> 2;  // 0..1: wave row (128 rows each)
  const int wn = wave & 3;   // 0..3: wave col (64 cols each)
  const int rowBase = blockIdx.x * BM;
  const int colBase = blockIdx.y * BN;

  const int soff = wave * 1024 + lane * 16;  // 512 thr x 16 B = 8 KB per call
  const signed char* gA0 = Ap + (size_t)(2 * blockIdx.x) * BAND_BYTES + soff;
  const signed char* gA1 = Ap + (size_t)(2 * blockIdx.x + 1) * BAND_BYTES + soff;
  const signed char* gB0 = Bp + (size_t)(2 * blockIdx.y) * BAND_BYTES + soff;
  const signed char* gB1 = Bp + (size_t)(2 * blockIdx.y + 1) * BAND_BYTES + soff;
  signed char* ldsA = (signed char*)As + soff;  // + slot*A_SLOT (+TILE half1)
  signed char* ldsB = (signed char*)Bs + soff;

  i32x4 acc[8][4] = {};

  const int fr = lane & 15;                            // fragment row/col
  const int fq = (((lane >> 4) ^ (fr & 3)) & 3) * 16;  // swizzled chunk slot

  // Per-wave read bases (swizzle uses (row&3) == (fr&3), invariant here).
  // A row = wm*128 + mi*16 + fr -> band wm, byte (mi*16+fr)*64 + fq.
  // B col = wn*64 + ni*16 + fr  -> band wn>>1, byte ((wn&1)*64+ni*16+fr)*64+fq.
  const int aoff = wm * TILE_BYTES + fr * 64 + fq;          // + mi*1024
  const int boff = (wn >> 1) * TILE_BYTES + ((wn & 1) * 64 + fr) * 64 + fq;  // + ni*1024

  // Prologue: stage K-tiles 0 and 1 into ring slots 0 and 1 (ordered groups).
  load_lds16(gA0, ldsA);
  load_lds16(gA1, ldsA + TILE_BYTES);
  load_lds16(gB0, ldsB);
  load_lds16(gB1, ldsB + TILE_BYTES);
  FENCE();
  load_lds16(gA0 + TILE_BYTES, ldsA + A_SLOT);
  load_lds16(gA1 + TILE_BYTES, ldsA + A_SLOT + TILE_BYTES);
  load_lds16(gB0 + TILE_BYTES, ldsB + B_SLOT);
  load_lds16(gB1 + TILE_BYTES, ldsB + B_SLOT + TILE_BYTES);

#pragma unroll
  for (int it = 0; it < NITER; ++it) {
    // Tile-readiness: drain own stage(it), keep stage(it+1) in flight.
    if (it + 1 < NITER) {
      asm volatile("s_waitcnt vmcnt(4) lgkmcnt(0)" ::: "memory");
    } else {
      asm volatile("s_waitcnt vmcnt(0) lgkmcnt(0)" ::: "memory");
    }
    BARRIER();  // slot it fully written by all waves; slot it-1 reads done

    const signed char* curA = As[it % 3] + aoff;
    const signed char* curB = Bs[it % 3] + boff;
    const int pslot = (it + 2) % 3;
    const size_t pgoff = (size_t)(it + 2) * TILE_BYTES;
    const bool pf = (it + 2) < NITER;

    i32x4 bf[4];
#pragma unroll
    for (int p = 0; p < 4; ++p) {
      // ---- read window: this phase's A pair (+ all B-frags in phase 0) ----
      if (p == 0) {
#pragma unroll
        for (int ni = 0; ni < 4; ++ni)
          bf[ni] = *(const i32x4*)(curB + ni * 1024);
      }
      i32x4 af0 = *(const i32x4*)(curA + (2 * p) * 1024);
      i32x4 af1 = *(const i32x4*)(curA + (2 * p + 1) * 1024);

      // ---- stage issue: one 8 KB piece of tile it+2 into ring slot ----
      if (pf) {
        if (p == 0) load_lds16(gA0 + pgoff, ldsA + pslot * A_SLOT);
        if (p == 1) load_lds16(gA1 + pgoff, ldsA + pslot * A_SLOT + TILE_BYTES);
        if (p == 2) load_lds16(gB0 + pgoff, ldsB + pslot * B_SLOT);
        if (p == 3) load_lds16(gB1 + pgoff, ldsB + pslot * B_SLOT + TILE_BYTES);
      }

      BARRIER();  // end read window (all waves), start MFMA window
      __builtin_amdgcn_s_setprio(1);
#pragma unroll
      for (int ni = 0; ni < 4; ++ni) {
        acc[2 * p][ni] =
            __builtin_amdgcn_mfma_i32_16x16x64_i8(af0, bf[ni], acc[2 * p][ni], 0, 0, 0);
        acc[2 * p + 1][ni] =
            __builtin_amdgcn_mfma_i32_16x16x64_i8(af1, bf[ni], acc[2 * p + 1][ni], 0, 0, 0);
      }
      __builtin_amdgcn_s_setprio(0);
      BARRIER();  // end MFMA window
    }
  }

  // Epilogue. C/D layout per 16x16: col = lane&15, row = (lane>>4)*4 + reg.
  const float sxw = sx[0] * sw[0];
  const int quad = lane >> 4;
#pragma unroll
  for (int mi = 0; mi < 8; ++mi) {
#pragma unroll
    for (int r = 0; r < 4; ++r) {
      const int s = rowBase + wm * 128 + mi * 16 + quad * 4 + r;
      const float rs = sxw / sy[s];
      float* orow = out + (size_t)s * O_DIM + colBase + wn * 64 + fr;
#pragma unroll
      for (int ni = 0; ni < 4; ++ni) {
        float f = rintf((float)acc[mi][ni][r] * rs);
        f = fminf(127.0f, fmaxf(-128.0f, f));
        orow[ni * 16] = f;
      }
    }
  }
}

extern "C" void kernel_launch(void* const* d_in, const int* in_sizes, int n_in,
                              void* d_out, int out_size, void* d_ws, size_t ws_size,
                              hipStream_t stream) {
  const int* x = (const int*)d_in[0];        // [S,K] int8 values as int32
  const int* w = (const int*)d_in[1];        // [O,K] int8 values as int32
  const float* sx = (const float*)d_in[2];
  const float* sw = (const float*)d_in[3];
  const float* sy = (const float*)d_in[4];   // [S]
  float* out = (float*)d_out;

  uint4* ap = (uint4*)d_ws;                                   // 8 MB tiled A
  uint4* bp = ap + (size_t)S_DIM * K_DIM / 16;                // 4 MB tiled B

  const int total = S_DIM * K_DIM / 16 + O_DIM * K_DIM / 16;  // 768K threads
  pack_kernel<<<(total + 255) / 256, 256, 0, stream>>>(
      x, w, sy, ap, bp, out + (size_t)S_DIM * O_DIM);

  dim3 grid(S_DIM / BM, O_DIM / BN);  // (32, 16)
  gemm_i8_kernel<<<grid, 512, 0, stream>>>(
      (const signed char*)ap, (const signed char*)bp, sx, sw, sy, out);
}

// Round 5
// 201.353 us; speedup vs baseline: 1.0544x; 1.0544x over previous
//
#include <hip/hip_runtime.h>

// Problem: S=8192, K=1024, O=4096
// out_q[s,o] = clip(round(int8dot(x[s,:], w[o,:]) * sx*sw/sy[s]), -128, 127)
// d_out = [ out_q as float (S*O) | scale_y (S) ]
//
// R10 = R8 (best, 199.6 us) + XCD supertile swizzle (T1 generalized).
// History: R7 ring-3@128^2 = 220.5 (occupancy loss); R8 ring-3@256x128,
// 16 waves/CU = 199.6 (counted-vmcnt null on 2-phase, as regime-gate
// predicts); R9 4-phase@256^2 = 212.3 (8-MFMA windows too small, 1 blk/CU).
// R10 attacks the untouched axis: L2/L3 read locality. Default x-fast +
// round-robin XCD dispatch streams ~256 MB of A/B re-reads through L3.
// Remap: each XCD owns an 8x-by-16y supertile (A 2MB + B 2MB, L2-resident)
// -> ~32 MB L3 reads. Bijective for grid 32x32 (1024 = 8*128).

#define S_DIM 8192
#define K_DIM 1024
#define O_DIM 4096
#define BM 256
#define BN 128
#define BK 64
#define NITER (K_DIM / BK)
#define TILE_BYTES (128 * BK)   // 8192 B band-tile (pack layout unit)
#define A_SLOT (2 * TILE_BYTES) // 16 KB: two band-tiles stacked
#define B_SLOT TILE_BYTES       // 8 KB

using i32x4 = __attribute__((ext_vector_type(4))) int;

__device__ __forceinline__ void load_lds16(const void* g, void* l) {
  __builtin_amdgcn_global_load_lds(
      (const __attribute__((address_space(1))) void*)g,
      (__attribute__((address_space(3))) void*)l, 16, 0, 0);
}

// ---------------- pack: int32 -> int8 into STAGING-TILE layout ----------------
// (byte-identical to the verified R5/R8 pack)
// Layout: tile t = band*16 + ktile (band = row/128, ktile = k/64), 8 KB each.
// Within tile: byte r*64 + cs*16 holds chunk (cs ^ (r&3)) of row band*128+r.
__global__ void pack_kernel(const int* __restrict__ xi, const int* __restrict__ wi,
                            const float* __restrict__ sy,
                            uint4* __restrict__ ap, uint4* __restrict__ bp,
                            float* __restrict__ out_sy) {
  const int tid = blockIdx.x * blockDim.x + threadIdx.x;
  const int nA = S_DIM * K_DIM / 16;  // 512K chunks
  const int nB = O_DIM * K_DIM / 16;  // 256K chunks

  const int* src;
  uint4* dst;
  int j;
  if (tid < nA) {
    src = xi; dst = ap; j = tid;
  } else if (tid < nA + nB) {
    src = wi; dst = bp; j = tid - nA;
  } else {
    return;
  }
  const int t = j >> 9;          // tile index (512 chunks/tile)
  const int idx = j & 511;
  const int r = idx >> 2;        // row within tile 0..127
  const int cs = idx & 3;        // chunk slot
  const int c = cs ^ (r & 3);    // global chunk (swizzle)
  const int band = t >> 4;       // 16 ktiles per band
  const int kt = t & 15;
  const int row = band * 128 + r;
  const int4* s4 = (const int4*)src + row * 256 + kt * 16 + c * 4;
  int4 v0 = s4[0], v1 = s4[1], v2 = s4[2], v3 = s4[3];
  uint4 o;
  o.x = (v0.x & 0xff) | ((v0.y & 0xff) << 8) | ((v0.z & 0xff) << 16) | (((unsigned)v0.w & 0xff) << 24);
  o.y = (v1.x & 0xff) | ((v1.y & 0xff) << 8) | ((v1.z & 0xff) << 16) | (((unsigned)v1.w & 0xff) << 24);
  o.z = (v2.x & 0xff) | ((v2.y & 0xff) << 8) | ((v2.z & 0xff) << 16) | (((unsigned)v2.w & 0xff) << 24);
  o.w = (v3.x & 0xff) | ((v3.y & 0xff) << 8) | ((v3.z & 0xff) << 16) | (((unsigned)v3.w & 0xff) << 24);
  dst[j] = o;
  if (tid < S_DIM) out_sy[tid] = sy[tid];
}

// ---------------- int8 MFMA GEMM, 256x128 tile, ring-3, 16 waves/CU ----------
// 512 threads = 8 waves in 4x2; wave owns 64x64 = 4x4 grid of 16x16x64 tiles.
// 3-slot LDS ring (72 KB, 2 blk/CU), 2-deep prefetch, counted waits:
//   s_waitcnt vmcnt(3) lgkmcnt(0) ; s_barrier ; issue stage(t+2) ; compute(t)
// XCD supertile swizzle: orig dispatch id round-robins XCDs (bid%8); give
// XCD k the supertile x in [ (k>>1)*8, +8 ), y in [ (k&1)*16, +16 ),
// x-fast within. Per-XCD working set: A 2MB + B(current panels) ~1MB -> L2.
__global__ __launch_bounds__(512, 4) void gemm_i8_kernel(
    const signed char* __restrict__ Ap,  // tiled-packed x
    const signed char* __restrict__ Bp,  // tiled-packed w
    const float* __restrict__ sx, const float* __restrict__ sw,
    const float* __restrict__ sy, float* __restrict__ out) {
  __shared__ __align__(16) signed char As[3][A_SLOT];  // 48 KB
  __shared__ __align__(16) signed char Bs[3][B_SLOT];  // 24 KB

  const int tid = threadIdx.x;
  const int wave = tid >> 6;
  const int lane = tid & 63;
  const int wm = wave >> 1;  // 0..3: wave row in block
  const int wn = wave & 1;   // 0..1: wave col in block

  // --- XCD supertile swizzle (bijective on 32x32 grid) ---
  const int orig = blockIdx.x + gridDim.x * blockIdx.y;  // HW dispatch order
  const int xcd = orig & 7;
  const int l = orig >> 3;            // 0..127 within XCD
  const int bx = (xcd >> 1) * 8 + (l & 7);    // 0..31
  const int by = (xcd & 1) * 16 + (l >> 3);   // 0..31

  const int rowBase = bx * BM;
  const int colBase = by * BN;

  const int soff = wave * 1024 + lane * 16;  // 8 waves cover 8 KB per call
  const signed char* gA0 = Ap + (size_t)(2 * bx) * NITER * TILE_BYTES + soff;
  const signed char* gA1 = Ap + (size_t)(2 * bx + 1) * NITER * TILE_BYTES + soff;
  const signed char* gB  = Bp + (size_t)by * NITER * TILE_BYTES + soff;
  signed char* ldsA = (signed char*)As + soff;  // + slot*A_SLOT (+TILE for half1)
  signed char* ldsB = (signed char*)Bs + soff;  // + slot*B_SLOT

  i32x4 acc[4][4] = {};

  const int fr = lane & 15;                            // fragment row
  const int fq = (((lane >> 4) ^ (fr & 3)) & 3) * 16;  // swizzled chunk slot

  // Prologue: stage K-tiles 0 and 1 into ring slots 0 and 1 (ordered groups).
  load_lds16(gA0, ldsA);
  load_lds16(gA1, ldsA + TILE_BYTES);
  load_lds16(gB, ldsB);
  asm volatile("" ::: "memory");
  {
    const size_t goff = TILE_BYTES;
    load_lds16(gA0 + goff, ldsA + A_SLOT);
    load_lds16(gA1 + goff, ldsA + A_SLOT + TILE_BYTES);
    load_lds16(gB + goff, ldsB + B_SLOT);
  }

#pragma unroll
  for (int it = 0; it < NITER; ++it) {
    // Drain own stage(it) (oldest 3); keep stage(it+1)'s 3 in flight.
    // lgkmcnt(0): no live ds_read of slot(it-1) before its overwrite below.
    if (it + 1 < NITER) {
      asm volatile("s_waitcnt vmcnt(3) lgkmcnt(0)" ::: "memory");
    } else {
      asm volatile("s_waitcnt vmcnt(0) lgkmcnt(0)" ::: "memory");
    }
    __builtin_amdgcn_s_barrier();
    asm volatile("" ::: "memory");  // no memory op crosses the barrier

    if (it + 2 < NITER) {  // 2-deep prefetch into ring slot (it+2)%3
      const int slot = (it + 2) % 3;
      const size_t goff = (size_t)(it + 2) * TILE_BYTES;
      load_lds16(gA0 + goff, ldsA + slot * A_SLOT);
      load_lds16(gA1 + goff, ldsA + slot * A_SLOT + TILE_BYTES);
      load_lds16(gB + goff, ldsB + slot * B_SLOT);
    }

    const signed char* curA = As[it % 3];
    const signed char* curB = Bs[it % 3];
    i32x4 bf[4];
#pragma unroll
    for (int ni = 0; ni < 4; ++ni)
      bf[ni] = *(const i32x4*)(curB + (wn * 64 + ni * 16 + fr) * BK + fq);

#pragma unroll
    for (int mi = 0; mi < 4; ++mi) {
      i32x4 af = *(const i32x4*)(curA + (wm * 64 + mi * 16 + fr) * BK + fq);
#pragma unroll
      for (int ni = 0; ni < 4; ++ni)
        acc[mi][ni] =
            __builtin_amdgcn_mfma_i32_16x16x64_i8(af, bf[ni], acc[mi][ni], 0, 0, 0);
    }
  }

  // Epilogue. C/D layout: col = lane&15, row = (lane>>4)*4 + reg.
  const float sxw = sx[0] * sw[0];
  const int quad = lane >> 4;
#pragma unroll
  for (int mi = 0; mi < 4; ++mi) {
#pragma unroll
    for (int r = 0; r < 4; ++r) {
      const int s = rowBase + wm * 64 + mi * 16 + quad * 4 + r;
      const float rs = sxw / sy[s];
      float* orow = out + (size_t)s * O_DIM + colBase + wn * 64 + fr;
#pragma unroll
      for (int ni = 0; ni < 4; ++ni) {
        float f = rintf((float)acc[mi][ni][r] * rs);
        f = fminf(127.0f, fmaxf(-128.0f, f));
        orow[ni * 16] = f;
      }
    }
  }
}

extern "C" void kernel_launch(void* const* d_in, const int* in_sizes, int n_in,
                              void* d_out, int out_size, void* d_ws, size_t ws_size,
                              hipStream_t stream) {
  const int* x = (const int*)d_in[0];        // [S,K] int8 values as int32
  const int* w = (const int*)d_in[1];        // [O,K] int8 values as int32
  const float* sx = (const float*)d_in[2];
  const float* sw = (const float*)d_in[3];
  const float* sy = (const float*)d_in[4];   // [S]
  float* out = (float*)d_out;

  uint4* ap = (uint4*)d_ws;                                   // 8 MB tiled A
  uint4* bp = ap + (size_t)S_DIM * K_DIM / 16;                // 4 MB tiled B

  const int total = S_DIM * K_DIM / 16 + O_DIM * K_DIM / 16;  // 768K threads
  pack_kernel<<<(total + 255) / 256, 256, 0, stream>>>(
      x, w, sy, ap, bp, out + (size_t)S_DIM * O_DIM);

  dim3 grid(S_DIM / BM, O_DIM / BN);  // (32, 32)
  gemm_i8_kernel<<<grid, 512, 0, stream>>>(
      (const signed char*)ap, (const signed char*)bp, sx, sw, sy, out);
}